// Round 1
// 884.514 us; speedup vs baseline: 1.1630x; 1.1630x over previous
//
#include <hip/hip_runtime.h>

#define B_TOT   20000
#define M_TOT   49
#define IN_DIM  128
#define OUT_DIM 128
#define TILE_B  128

typedef short v8s __attribute__((ext_vector_type(8)));
typedef float v4f __attribute__((ext_vector_type(4)));

__device__ __forceinline__ short f2bf(float x) {
    union { float f; unsigned int u; } c; c.f = x;
    unsigned int r = c.u + 0x7FFFu + ((c.u >> 16) & 1u);   // RNE
    return (short)(r >> 16);
}

// One block: one m (one l), one 128-row b-tile. 256 threads = 4 waves.
// W[l] (128x128) staged ONCE to LDS as bf16 (XOR-swizzled) -> 32 KiB LDS only.
// A is streamed directly global->VGPR->bf16 fragments (no A LDS, no A barrier);
// kk+1 chunk prefetched while kk computes.
// mfma(bf, af) (swapped operands): lane holds 4 CONSECUTIVE out-channels of one
// b-row -> float4 epilogue stores.
__global__ __launch_bounds__(256, 3)
void so3_linear_kernel(const float* __restrict__ inp,
                       const float* __restrict__ wgt,
                       const float* __restrict__ bias,
                       float* __restrict__ out) {
    __shared__ __align__(16) short Ws[OUT_DIM][IN_DIM];   // 32 KB

    const int tid  = threadIdx.x;
    const int m    = blockIdx.y;
    const int b0   = blockIdx.x * TILE_B;

    int l = 0;
    while ((l + 1) * (l + 1) <= m) ++l;   // l = floor(sqrt(m))

    const int wave = tid >> 6;
    const int lane = tid & 63;
    const int lr   = lane & 15;
    const int quad = lane >> 4;
    const int wrow = (wave >> 1) * 64;
    const int wcol = (wave & 1) * 64;

    // Per-i A row pointers (clamped; stores are guarded instead).
    const float* arow[4];
    #pragma unroll
    for (int i = 0; i < 4; ++i) {
        int gb = b0 + wrow + i * 16 + lr;
        int gc = gb < B_TOT ? gb : B_TOT - 1;
        arow[i] = inp + ((size_t)gc * M_TOT + m) * IN_DIM + quad * 8;
    }

    // Prefetch kk=0 A chunk — HBM latency hides under W staging.
    float4 pa[4][2];
    #pragma unroll
    for (int i = 0; i < 4; ++i) {
        pa[i][0] = *(const float4*)(arow[i]);
        pa[i][1] = *(const float4*)(arow[i] + 4);
    }

    // ---- stage W[l]: 128 x 128 fp32 -> bf16 LDS (16B-chunk XOR swizzle) ----
    const float4* wp4 = (const float4*)(wgt + (size_t)l * OUT_DIM * IN_DIM);
    #pragma unroll
    for (int it = 0; it < 16; ++it) {
        int f  = it * 256 + tid;
        int r  = f >> 5;
        int c4 = f & 31;
        float4 v = wp4[r * (IN_DIM / 4) + c4];
        short4 s;
        s.x = f2bf(v.x); s.y = f2bf(v.y); s.z = f2bf(v.z); s.w = f2bf(v.w);
        int sc = (((c4 >> 1) ^ (r & 15)) << 3) + ((c4 & 1) << 2);
        *(short4*)&Ws[r][sc] = s;
    }

    __syncthreads();

    v4f acc[4][4];
    #pragma unroll
    for (int i = 0; i < 4; ++i)
        #pragma unroll
        for (int j = 0; j < 4; ++j)
            acc[i][j] = (v4f)(0.f);

    #pragma unroll
    for (int kk = 0; kk < 4; ++kk) {
        // Convert the prefetched A chunk to bf16 fragments.
        v8s af[4];
        #pragma unroll
        for (int i = 0; i < 4; ++i) {
            af[i][0] = f2bf(pa[i][0].x); af[i][1] = f2bf(pa[i][0].y);
            af[i][2] = f2bf(pa[i][0].z); af[i][3] = f2bf(pa[i][0].w);
            af[i][4] = f2bf(pa[i][1].x); af[i][5] = f2bf(pa[i][1].y);
            af[i][6] = f2bf(pa[i][1].z); af[i][7] = f2bf(pa[i][1].w);
        }
        // Prefetch next chunk (overlaps LDS reads + MFMA below).
        if (kk < 3) {
            #pragma unroll
            for (int i = 0; i < 4; ++i) {
                pa[i][0] = *(const float4*)(arow[i] + (kk + 1) * 32);
                pa[i][1] = *(const float4*)(arow[i] + (kk + 1) * 32 + 4);
            }
        }
        const int chunk = kk * 4 + quad;             // 16B-chunk index along K
        const int sc    = ((chunk ^ lr) << 3);       // swizzled short offset
        v8s bf[4];
        #pragma unroll
        for (int j = 0; j < 4; ++j)
            bf[j] = *(const v8s*)&Ws[wcol + j * 16 + lr][sc];
        #pragma unroll
        for (int i = 0; i < 4; ++i)
            #pragma unroll
            for (int j = 0; j < 4; ++j)
                acc[i][j] = __builtin_amdgcn_mfma_f32_16x16x32_bf16(
                                bf[j], af[i], acc[i][j], 0, 0, 0);
    }

    // ---- epilogue: lane (quad,lr), tile (i,j) holds
    // out[b0+wrow+i*16+lr][m][wcol+j*16+quad*4 .. +3] -> float4 stores ----
    #pragma unroll
    for (int i = 0; i < 4; ++i) {
        const int gb = b0 + wrow + i * 16 + lr;
        if (gb < B_TOT) {
            float* orow = out + ((size_t)gb * M_TOT + m) * OUT_DIM;
            #pragma unroll
            for (int j = 0; j < 4; ++j) {
                const int col = wcol + j * 16 + quad * 4;
                v4f v = acc[i][j];
                if (m == 0) {
                    v[0] += bias[col];
                    v[1] += bias[col + 1];
                    v[2] += bias[col + 2];
                    v[3] += bias[col + 3];
                }
                *(v4f*)(orow + col) = v;
            }
        }
    }
}

extern "C" void kernel_launch(void* const* d_in, const int* in_sizes, int n_in,
                              void* d_out, int out_size, void* d_ws, size_t ws_size,
                              hipStream_t stream) {
    const float* inp  = (const float*)d_in[0];   // [20000, 49, 128] f32
    const float* wgt  = (const float*)d_in[1];   // [7, 128, 128]   f32
    const float* bias = (const float*)d_in[2];   // [128]           f32
    float* out = (float*)d_out;                  // [20000, 49, 128] f32

    dim3 grid((B_TOT + TILE_B - 1) / TILE_B, M_TOT);  // 157 x 49
    dim3 block(256);
    so3_linear_kernel<<<grid, block, 0, stream>>>(inp, wgt, bias, out);
}